// Round 5
// baseline (327.401 us; speedup 1.0000x reference)
//
#include <hip/hip_runtime.h>
#include <hip/hip_bf16.h>

// SwitchMoE: N=16384, D=512, F=2048, E=8, top-1. Sparse one-expert-per-token.
// R5: persistent grid-stride GEMM blocks (grid 512 = 2/CU, XCD-affine) with
// cross-tile double-buffered LDS pipeline: loads(s+1) issued after the
// barrier overlap compute(s); barrier vmcnt-drain lands on the consumed
// buffer. Router+weight-transpose merged into one kernel.

typedef unsigned short u16;
typedef unsigned int u32;
typedef __bf16 bf16x8 __attribute__((ext_vector_type(8)));
typedef u16 u16x8 __attribute__((ext_vector_type(8)));
typedef float f32x4 __attribute__((ext_vector_type(4)));

#define N_TOK 16384
#define DIM   512
#define FDIM  2048
#define NEXP  8

__device__ inline u16 f2bf(float f) {
    u32 u = __float_as_uint(f);
    u = (u + 0x7FFF + ((u >> 16) & 1)) >> 16;  // RNE
    return (u16)u;
}

__device__ inline void gload16(const u16* g, u16* l) {
    __builtin_amdgcn_global_load_lds(
        (const __attribute__((address_space(1))) u32*)g,
        (__attribute__((address_space(3))) u32*)l, 16, 0, 0);
}

// Walk counts -> (expert, row0, rows) for 128-row m-slot `ms`.
__device__ inline bool decode_ms(const int* __restrict__ counts, int ms,
                                 int& e, int& row0, int& rows) {
    int t = 0, s = 0;
    for (int ee = 0; ee < NEXP; ++ee) {
        int c = counts[ee];
        int ntile = (c + 127) >> 7;
        if (ms < t + ntile) {
            int r = (ms - t) << 7;
            e = ee; row0 = s + r; rows = (c - r < 128) ? (c - r) : 128;
            return true;
        }
        t += ntile; s += c;
    }
    return false;
}

// ---------------- k_pre: weight transpose (blocks 0..2047) + router (2048..) -
__device__ void wt_body(char* smem, int lb0, const float* __restrict__ W1,
                        const float* __restrict__ W2, u16* __restrict__ w1t,
                        u16* __restrict__ w2t) {
    float (*tile)[65] = (float(*)[65])smem;   // 64x65 fp32
    const int isW2 = lb0 >= 1024;
    const float* srcM = isW2 ? W2 : W1;
    u16* dstM = isW2 ? w2t : w1t;
    const int R = isW2 ? FDIM : DIM;
    const int C = isW2 ? DIM : FDIM;
    const int cT = C / 64;
    const int lb = isW2 ? lb0 - 1024 : lb0;
    for (int it = 0; it < 2; ++it) {
        const int gt = lb * 2 + it;
        const int e = gt >> 8;            // 256 tiles per expert-matrix
        const int rem = gt & 255;
        const int r0 = (rem / cT) * 64, c0 = (rem % cT) * 64;
        const float* s = srcM + (size_t)e * R * C;
        u16* d = dstM + (size_t)e * R * C;
        __syncthreads();
        const int lr = threadIdx.x >> 4;
        const int lc = (threadIdx.x & 15) * 4;
        for (int i = 0; i < 4; ++i) {
            int r = lr + i * 16;
            float4 v = *(const float4*)(s + (size_t)(r0 + r) * C + c0 + lc);
            tile[r][lc] = v.x; tile[r][lc + 1] = v.y;
            tile[r][lc + 2] = v.z; tile[r][lc + 3] = v.w;
        }
        __syncthreads();
        const int oc = threadIdx.x >> 3;
        const int orr = (threadIdx.x & 7) * 8;
        for (int p = 0; p < 2; ++p) {
            int c = oc + p * 32;
            u16x8 v;
            for (int j = 0; j < 8; ++j) v[j] = f2bf(tile[orr + j][c]);
            *(u16x8*)(d + (size_t)(c0 + c) * R + r0 + orr) = v;
        }
    }
}

__device__ void router_body(char* smem, int rb, const float* __restrict__ x,
                            const float* __restrict__ Wg, int* __restrict__ top1,
                            float* __restrict__ topval, int* __restrict__ pos,
                            int* __restrict__ counts, float* __restrict__ denom) {
    float4* wgs4 = (float4*)smem;                       // 1024 float4 = 16 KB
    int*   lcnt   = (int*)(smem + 16384);
    float* lden   = (float*)(smem + 16384 + 32);
    int*   lbase  = (int*)(smem + 16384 + 64);
    int*   ltok_e = (int*)(smem + 16384 + 96);
    int*   ltok_r = (int*)(smem + 16384 + 224);
    const int tid = threadIdx.x;
    const int lane = tid & 63, wv = tid >> 6;
    for (int i = tid; i < NEXP * 128; i += 256) wgs4[i] = ((const float4*)Wg)[i];
    if (tid < NEXP) { lcnt[tid] = 0; lden[tid] = 0.f; }
    __syncthreads();
    const int tok0 = rb * 32;
    for (int tt = 0; tt < 8; ++tt) {
        const int tloc = wv * 8 + tt;
        const int n = tok0 + tloc;
        const float4* xr = (const float4*)(x + (size_t)n * DIM);
        float4 a = xr[lane], b = xr[64 + lane];
        float p[NEXP];
#pragma unroll
        for (int e = 0; e < NEXP; ++e) {
            float4 wa = wgs4[e * 128 + lane], wb = wgs4[e * 128 + 64 + lane];
            p[e] = a.x * wa.x + a.y * wa.y + a.z * wa.z + a.w * wa.w
                 + b.x * wb.x + b.y * wb.y + b.z * wb.z + b.w * wb.w;
        }
#pragma unroll
        for (int e = 0; e < NEXP; ++e)
#pragma unroll
            for (int m = 32; m >= 1; m >>= 1)
                p[e] += __shfl_xor(p[e], m, 64);
        if (lane == 0) {
            float best = p[0]; int be = 0;
#pragma unroll
            for (int e = 1; e < NEXP; ++e)
                if (p[e] > best) { best = p[e]; be = e; }  // strict >: jnp.argmax
            top1[n] = be;
            topval[n] = best;
            ltok_e[tloc] = be;
            ltok_r[tloc] = atomicAdd(&lcnt[be], 1);
            atomicAdd(&lden[be], best);
        }
    }
    __syncthreads();
    if (tid < NEXP) {
        int c = lcnt[tid];
        lbase[tid] = c ? atomicAdd(&counts[tid], c) : 0;
        float dsum = lden[tid];
        if (dsum != 0.f) atomicAdd(&denom[tid], dsum);
    }
    __syncthreads();
    if (tid < 32) {
        int n = tok0 + tid;
        pos[n] = lbase[ltok_e[tid]] + ltok_r[tid];
    }
}

__global__ __launch_bounds__(256) void k_pre(
    const float* __restrict__ W1, const float* __restrict__ W2,
    u16* __restrict__ w1t, u16* __restrict__ w2t,
    const float* __restrict__ x, const float* __restrict__ Wg,
    int* __restrict__ top1, float* __restrict__ topval,
    int* __restrict__ pos, int* __restrict__ counts, float* __restrict__ denom) {
    __shared__ __align__(16) char smem[16832];
    const int b = blockIdx.x;
    if (b < 512) router_body(smem, b, x, Wg, top1, topval, pos, counts, denom);
    else wt_body(smem, b - 512, W1, W2, w1t, w2t);
}

// ---------------- Gather: 32 tokens/block -> expert-contiguous bf16 ----------
__global__ __launch_bounds__(256) void k_gather(
    const float* __restrict__ x, const int* __restrict__ top1,
    const int* __restrict__ pos, const int* __restrict__ counts,
    int* __restrict__ perm, u16* __restrict__ xg) {
    __shared__ int soffs[NEXP];
    if (threadIdx.x == 0) {
        int s = 0;
        for (int e = 0; e < NEXP; ++e) { soffs[e] = s; s += counts[e]; }
    }
    __syncthreads();
    const int wid = threadIdx.x >> 6, lane = threadIdx.x & 63;
    const int n0 = blockIdx.x * 32 + wid * 8;
    for (int tt = 0; tt < 8; ++tt) {
        const int n = n0 + tt;
        const int e = top1[n];
        const int dst = soffs[e] + pos[n];
        if (lane == 0) perm[dst] = n;
        const float4* src = (const float4*)(x + (size_t)n * DIM);
        float4 a = src[lane * 2], b = src[lane * 2 + 1];
        u16x8 v;
        v[0] = f2bf(a.x); v[1] = f2bf(a.y); v[2] = f2bf(a.z); v[3] = f2bf(a.w);
        v[4] = f2bf(b.x); v[5] = f2bf(b.y); v[6] = f2bf(b.z); v[7] = f2bf(b.w);
        *(u16x8*)(xg + (size_t)dst * DIM + lane * 8) = v;
    }
}

// ---------------- GEMM1: hb = relu(xg @ W1 + b1) -----------------------------
// Persistent: grid 512, tile slots t = cx + 8*(nt + 16*j), cx = t&7 = XCD.
// Double-buffered LDS, pipeline carried across tiles.
__global__ __launch_bounds__(256) void k_ffn1(
    const u16* __restrict__ xg, const u16* __restrict__ w1t,
    const float* __restrict__ b1, const int* __restrict__ counts,
    u16* __restrict__ hb) {
    __shared__ u16 as[2][128 * 64];
    __shared__ u16 bs[2][128 * 64];
    const int tid = threadIdx.x;
    const int lane = tid & 63, wid = tid >> 6;
    const int wr = wid >> 1, wc = wid & 1;
    const int q = lane >> 4, l15 = lane & 15;

    auto tile_ok = [&](int tt, int& e, int& row0, int& rows, int& nt) -> bool {
        int cx = tt & 7, r = tt >> 3;
        nt = r & 15;
        int ms = cx + 8 * (r >> 4);
        return decode_ms(counts, ms, e, row0, rows);
    };
    auto issue = [&](int bsel, int e_, int row0_, int rows_, int nt_, int k0_) {
        const u16* B = w1t + (size_t)e_ * FDIM * DIM;
        for (int it = 0; it < 4; ++it) {
            int chunk = it * 256 + tid;
            int row = chunk >> 3, c = chunk & 7;
            int gcol = c ^ (row & 7);  // XOR swizzle
            int rr = row < rows_ ? row : rows_ - 1;
            gload16(xg + (size_t)(row0_ + rr) * DIM + k0_ + gcol * 8, &as[bsel][chunk * 8]);
            int gb = nt_ * 128 + row;
            gload16(B + (size_t)gb * DIM + k0_ + gcol * 8, &bs[bsel][chunk * 8]);
        }
    };

    int t = blockIdx.x;
    int e, row0, rows, nt;
    while (t < 2176 && !tile_ok(t, e, row0, rows, nt)) t += 512;
    if (t >= 2176) return;
    issue(0, e, row0, rows, nt, 0);

    f32x4 acc[4][4];
#pragma unroll
    for (int i = 0; i < 4; ++i)
#pragma unroll
        for (int j = 0; j < 4; ++j) acc[i][j] = f32x4{0.f, 0.f, 0.f, 0.f};

    int k0 = 0, buf = 0;
    while (true) {
        // next step lookahead
        int t2 = t, k2 = k0 + 64, e2 = e, row02 = row0, rows2 = rows, nt2 = nt;
        bool more = true;
        if (k2 == DIM) {
            k2 = 0;
            t2 = t + 512;
            while (t2 < 2176 && !tile_ok(t2, e2, row02, rows2, nt2)) t2 += 512;
            if (t2 >= 2176) more = false;
        }
        __syncthreads();                       // drains vmcnt -> buf[buf] ready
        if (more) issue(buf ^ 1, e2, row02, rows2, nt2, k2);
        const u16* asb = as[buf];
        const u16* bsb = bs[buf];
#pragma unroll
        for (int ks = 0; ks < 64; ks += 32) {
            bf16x8 af[4], bfr[4];
#pragma unroll
            for (int mi = 0; mi < 4; ++mi) {
                int m = wr * 64 + mi * 16 + l15;
                int cc = ((ks >> 3) + q) ^ (m & 7);
                af[mi] = *(const bf16x8*)(asb + m * 64 + cc * 8);
            }
#pragma unroll
            for (int ni = 0; ni < 4; ++ni) {
                int n = wc * 64 + ni * 16 + l15;
                int cc = ((ks >> 3) + q) ^ (n & 7);
                bfr[ni] = *(const bf16x8*)(bsb + n * 64 + cc * 8);
            }
#pragma unroll
            for (int mi = 0; mi < 4; ++mi)
#pragma unroll
                for (int ni = 0; ni < 4; ++ni)
                    acc[mi][ni] = __builtin_amdgcn_mfma_f32_16x16x32_bf16(
                        af[mi], bfr[ni], acc[mi][ni], 0, 0, 0);
        }
        if (k0 == DIM - 64) {
            const float* b1e = b1 + e * FDIM + nt * 128;
            float bcol[4];
#pragma unroll
            for (int ni = 0; ni < 4; ++ni) bcol[ni] = b1e[wc * 64 + ni * 16 + l15];
#pragma unroll
            for (int mi = 0; mi < 4; ++mi) {
#pragma unroll
                for (int r = 0; r < 4; ++r) {
                    int mrow = wr * 64 + mi * 16 + q * 4 + r;
                    if (mrow >= rows) continue;
                    size_t base = (size_t)(row0 + mrow) * FDIM + nt * 128;
#pragma unroll
                    for (int ni = 0; ni < 4; ++ni) {
                        float v = acc[mi][ni][r] + bcol[ni];
                        v = v > 0.f ? v : 0.f;
                        hb[base + wc * 64 + ni * 16 + l15] = f2bf(v);
                    }
                }
            }
#pragma unroll
            for (int i = 0; i < 4; ++i)
#pragma unroll
                for (int j = 0; j < 4; ++j) acc[i][j] = f32x4{0.f, 0.f, 0.f, 0.f};
            if (!more) break;
        }
        buf ^= 1; k0 = k2; t = t2; e = e2; row0 = row02; rows = rows2; nt = nt2;
    }
}

// ---------------- GEMM2: out[tok] = gate*(hb @ W2 + b2), 128x64 tiles --------
__global__ __launch_bounds__(256) void k_ffn2(
    const u16* __restrict__ hb, const u16* __restrict__ w2t,
    const float* __restrict__ b2, const int* __restrict__ counts,
    const int* __restrict__ perm, const float* __restrict__ topval,
    const float* __restrict__ denom, float* __restrict__ out) {
    __shared__ u16 as[2][128 * 64];   // 32 KB
    __shared__ u16 bs[2][64 * 64];    // 16 KB
    const int tid = threadIdx.x;
    const int lane = tid & 63, w = tid >> 6;
    const int q = lane >> 4, l15 = lane & 15;

    auto tile_ok = [&](int tt, int& e, int& row0, int& rows, int& nt) -> bool {
        int cx = tt & 7, r = tt >> 3;
        nt = r & 7;
        int ms = cx + 8 * (r >> 3);
        return decode_ms(counts, ms, e, row0, rows);
    };
    auto issue = [&](int bsel, int e_, int row0_, int rows_, int nt_, int k0_) {
        const u16* B = w2t + (size_t)e_ * DIM * FDIM + (size_t)(nt_ * 64) * FDIM;
        for (int it = 0; it < 6; ++it) {
            if (it < 4) {
                int chunk = it * 256 + tid;
                int row = chunk >> 3, c = chunk & 7;
                int gcol = c ^ (row & 7);
                int rr = row < rows_ ? row : rows_ - 1;
                gload16(hb + (size_t)(row0_ + rr) * FDIM + k0_ + gcol * 8, &as[bsel][chunk * 8]);
            } else {
                int chunk = (it - 4) * 256 + tid;
                int row = chunk >> 3, c = chunk & 7;
                int gcol = c ^ (row & 7);
                gload16(B + (size_t)row * FDIM + k0_ + gcol * 8, &bs[bsel][chunk * 8]);
            }
        }
    };

    int t = blockIdx.x;
    int e, row0, rows, nt;
    while (t < 1088 && !tile_ok(t, e, row0, rows, nt)) t += 512;
    if (t >= 1088) return;
    issue(0, e, row0, rows, nt, 0);

    f32x4 acc[2][4];
#pragma unroll
    for (int i = 0; i < 2; ++i)
#pragma unroll
        for (int j = 0; j < 4; ++j) acc[i][j] = f32x4{0.f, 0.f, 0.f, 0.f};

    int k0 = 0, buf = 0;
    while (true) {
        int t2 = t, k2 = k0 + 64, e2 = e, row02 = row0, rows2 = rows, nt2 = nt;
        bool more = true;
        if (k2 == FDIM) {
            k2 = 0;
            t2 = t + 512;
            while (t2 < 1088 && !tile_ok(t2, e2, row02, rows2, nt2)) t2 += 512;
            if (t2 >= 1088) more = false;
        }
        __syncthreads();
        if (more) issue(buf ^ 1, e2, row02, rows2, nt2, k2);
        const u16* asb = as[buf];
        const u16* bsb = bs[buf];
#pragma unroll
        for (int ks = 0; ks < 64; ks += 32) {
            bf16x8 af[2], bfr[4];
#pragma unroll
            for (int mi = 0; mi < 2; ++mi) {
                int m = w * 32 + mi * 16 + l15;
                int cc = ((ks >> 3) + q) ^ (m & 7);
                af[mi] = *(const bf16x8*)(asb + m * 64 + cc * 8);
            }
#pragma unroll
            for (int ni = 0; ni < 4; ++ni) {
                int n = ni * 16 + l15;
                int cc = ((ks >> 3) + q) ^ (n & 7);
                bfr[ni] = *(const bf16x8*)(bsb + n * 64 + cc * 8);
            }
#pragma unroll
            for (int mi = 0; mi < 2; ++mi)
#pragma unroll
                for (int ni = 0; ni < 4; ++ni)
                    acc[mi][ni] = __builtin_amdgcn_mfma_f32_16x16x32_bf16(
                        af[mi], bfr[ni], acc[mi][ni], 0, 0, 0);
        }
        if (k0 == FDIM - 64) {
            const float scale = 16384.0f / (denom[e] + 1e-6f);
            float bcol[4];
#pragma unroll
            for (int ni = 0; ni < 4; ++ni)
                bcol[ni] = b2[e * DIM + nt * 64 + ni * 16 + l15];
#pragma unroll
            for (int mi = 0; mi < 2; ++mi) {
#pragma unroll
                for (int r = 0; r < 4; ++r) {
                    int mrow = w * 32 + mi * 16 + q * 4 + r;
                    if (mrow >= rows) continue;
                    int tok = perm[row0 + mrow];
                    float g = topval[tok] * scale;
                    size_t base = (size_t)tok * DIM + nt * 64;
#pragma unroll
                    for (int ni = 0; ni < 4; ++ni) {
                        float v = acc[mi][ni][r] + bcol[ni];
                        out[base + ni * 16 + l15] = g * v;
                    }
                }
            }
#pragma unroll
            for (int i = 0; i < 2; ++i)
#pragma unroll
                for (int j = 0; j < 4; ++j) acc[i][j] = f32x4{0.f, 0.f, 0.f, 0.f};
            if (!more) break;
        }
        buf ^= 1; k0 = k2; t = t2; e = e2; row0 = row02; rows = rows2; nt = nt2;
    }
}

extern "C" void kernel_launch(void* const* d_in, const int* in_sizes, int n_in,
                              void* d_out, int out_size, void* d_ws, size_t ws_size,
                              hipStream_t stream) {
    const float* x  = (const float*)d_in[0];
    const float* Wg = (const float*)d_in[1];
    const float* W1 = (const float*)d_in[2];
    const float* b1 = (const float*)d_in[3];
    const float* W2 = (const float*)d_in[4];
    const float* b2 = (const float*)d_in[5];
    float* out = (float*)d_out;

    char* W = (char*)d_ws;
    int*   counts = (int*)W;                // 8 ints
    float* denom  = (float*)(W + 64);       // 8 floats
    int*   top1   = (int*)(W + 4096);
    float* topval = (float*)(W + 4096 + 65536);
    int*   pos    = (int*)(W + 4096 + 131072);
    int*   perm   = (int*)(W + 4096 + 196608);
    u16*   xg     = (u16*)(W + 266240);                  // N*D bf16 = 16 MB
    u16*   w1t    = xg  + (size_t)N_TOK * DIM;           // E*F*D bf16 = 16 MB
    u16*   w2t    = w1t + (size_t)NEXP * FDIM * DIM;     // E*D*F bf16 = 16 MB
    u16*   hb     = w2t + (size_t)NEXP * DIM * FDIM;     // N*F bf16 = 64 MB

    hipMemsetAsync(W, 0, 128, stream);  // counts + denom
    k_pre<<<2560, 256, 0, stream>>>(W1, W2, w1t, w2t, x, Wg, top1, topval, pos, counts, denom);
    k_gather<<<N_TOK / 32, 256, 0, stream>>>(x, top1, pos, counts, perm, xg);
    k_ffn1<<<512, 256, 0, stream>>>(xg, w1t, b1, counts, hb);
    k_ffn2<<<512, 256, 0, stream>>>(hb, w2t, b2, counts, perm, topval, denom, out);
}

// Round 6
// 270.714 us; speedup vs baseline: 1.2094x; 1.2094x over previous
//
#include <hip/hip_runtime.h>
#include <hip/hip_bf16.h>

// SwitchMoE: N=16384, D=512, F=2048, E=8, top-1. Sparse one-expert-per-token.
// R6: revert R5's persistent/dbuf experiment (regressed: residency 4->2
// blocks/CU outweighed pipelining). R4 single-buffer 2-barrier K-loop
// structure; ffn1 BM=64 for 4 blocks/CU; gather folded into router (xg is
// token-order bf16 cast, ffn1 reads A rows via perm indirection).

typedef unsigned short u16;
typedef unsigned int u32;
typedef __bf16 bf16x8 __attribute__((ext_vector_type(8)));
typedef u16 u16x8 __attribute__((ext_vector_type(8)));
typedef float f32x4 __attribute__((ext_vector_type(4)));

#define N_TOK 16384
#define DIM   512
#define FDIM  2048
#define NEXP  8

__device__ inline u16 f2bf(float f) {
    u32 u = __float_as_uint(f);
    u = (u + 0x7FFF + ((u >> 16) & 1)) >> 16;  // RNE
    return (u16)u;
}

__device__ inline void gload16(const u16* g, u16* l) {
    __builtin_amdgcn_global_load_lds(
        (const __attribute__((address_space(1))) u32*)g,
        (__attribute__((address_space(3))) u32*)l, 16, 0, 0);
}

// Walk counts -> (expert, row0, rows) for 64-row m-slot `ms` (<=263 slots).
__device__ inline bool decode_ms64(const int* __restrict__ counts, int ms,
                                   int& e, int& row0, int& rows) {
    int t = 0, s = 0;
    for (int ee = 0; ee < NEXP; ++ee) {
        int c = counts[ee];
        int ntile = (c + 63) >> 6;
        if (ms < t + ntile) {
            int r = (ms - t) << 6;
            e = ee; row0 = s + r; rows = (c - r < 64) ? (c - r) : 64;
            return true;
        }
        t += ntile; s += c;
    }
    return false;
}

// 128-row m-slot variant for ffn2 (<=135 slots).
__device__ inline bool decode_ms128(const int* __restrict__ counts, int ms,
                                    int& e, int& row0, int& rows) {
    int t = 0, s = 0;
    for (int ee = 0; ee < NEXP; ++ee) {
        int c = counts[ee];
        int ntile = (c + 127) >> 7;
        if (ms < t + ntile) {
            int r = (ms - t) << 7;
            e = ee; row0 = s + r; rows = (c - r < 128) ? (c - r) : 128;
            return true;
        }
        t += ntile; s += c;
    }
    return false;
}

// ---------------- k_pre: router+xg-cast (blocks 0..511) | wt (512..2559) -----
__device__ void wt_body(char* smem, int lb0, const float* __restrict__ W1,
                        const float* __restrict__ W2, u16* __restrict__ w1t,
                        u16* __restrict__ w2t) {
    float (*tile)[65] = (float(*)[65])smem;   // 64x65 fp32
    const int isW2 = lb0 >= 1024;
    const float* srcM = isW2 ? W2 : W1;
    u16* dstM = isW2 ? w2t : w1t;
    const int R = isW2 ? FDIM : DIM;
    const int C = isW2 ? DIM : FDIM;
    const int cT = C / 64;
    const int lb = isW2 ? lb0 - 1024 : lb0;
    for (int it = 0; it < 2; ++it) {
        const int gt = lb * 2 + it;
        const int e = gt >> 8;            // 256 tiles per expert-matrix
        const int rem = gt & 255;
        const int r0 = (rem / cT) * 64, c0 = (rem % cT) * 64;
        const float* s = srcM + (size_t)e * R * C;
        u16* d = dstM + (size_t)e * R * C;
        __syncthreads();
        const int lr = threadIdx.x >> 4;
        const int lc = (threadIdx.x & 15) * 4;
        for (int i = 0; i < 4; ++i) {
            int r = lr + i * 16;
            float4 v = *(const float4*)(s + (size_t)(r0 + r) * C + c0 + lc);
            tile[r][lc] = v.x; tile[r][lc + 1] = v.y;
            tile[r][lc + 2] = v.z; tile[r][lc + 3] = v.w;
        }
        __syncthreads();
        const int oc = threadIdx.x >> 3;
        const int orr = (threadIdx.x & 7) * 8;
        for (int p = 0; p < 2; ++p) {
            int c = oc + p * 32;
            u16x8 v;
            for (int j = 0; j < 8; ++j) v[j] = f2bf(tile[orr + j][c]);
            *(u16x8*)(d + (size_t)(c0 + c) * R + r0 + orr) = v;
        }
    }
}

__device__ void router_body(char* smem, int rb, const float* __restrict__ x,
                            const float* __restrict__ Wg, int* __restrict__ top1,
                            float* __restrict__ topval, int* __restrict__ pos,
                            int* __restrict__ counts, float* __restrict__ denom,
                            u16* __restrict__ xg) {
    float4* wgs4 = (float4*)smem;                       // 16 KB
    int*   lcnt   = (int*)(smem + 16384);
    float* lden   = (float*)(smem + 16384 + 32);
    int*   lbase  = (int*)(smem + 16384 + 64);
    int*   ltok_e = (int*)(smem + 16384 + 96);
    int*   ltok_r = (int*)(smem + 16384 + 224);
    const int tid = threadIdx.x;
    const int lane = tid & 63, wv = tid >> 6;
    for (int i = tid; i < NEXP * 128; i += 256) wgs4[i] = ((const float4*)Wg)[i];
    if (tid < NEXP) { lcnt[tid] = 0; lden[tid] = 0.f; }
    __syncthreads();
    const int tok0 = rb * 32;
    for (int tt = 0; tt < 8; ++tt) {
        const int tloc = wv * 8 + tt;
        const int n = tok0 + tloc;
        const float4* xr = (const float4*)(x + (size_t)n * DIM);
        float4 a = xr[lane], b = xr[64 + lane];
        // fused x -> bf16 cast (token order); replaces k_gather entirely
        {
            ushort4 va, vb;
            va.x = f2bf(a.x); va.y = f2bf(a.y); va.z = f2bf(a.z); va.w = f2bf(a.w);
            vb.x = f2bf(b.x); vb.y = f2bf(b.y); vb.z = f2bf(b.z); vb.w = f2bf(b.w);
            *(ushort4*)(xg + (size_t)n * DIM + 4 * lane) = va;
            *(ushort4*)(xg + (size_t)n * DIM + 256 + 4 * lane) = vb;
        }
        float p[NEXP];
#pragma unroll
        for (int e = 0; e < NEXP; ++e) {
            float4 wa = wgs4[e * 128 + lane], wb = wgs4[e * 128 + 64 + lane];
            p[e] = a.x * wa.x + a.y * wa.y + a.z * wa.z + a.w * wa.w
                 + b.x * wb.x + b.y * wb.y + b.z * wb.z + b.w * wb.w;
        }
#pragma unroll
        for (int e = 0; e < NEXP; ++e)
#pragma unroll
            for (int m = 32; m >= 1; m >>= 1)
                p[e] += __shfl_xor(p[e], m, 64);
        if (lane == 0) {
            float best = p[0]; int be = 0;
#pragma unroll
            for (int e = 1; e < NEXP; ++e)
                if (p[e] > best) { best = p[e]; be = e; }  // strict >: jnp.argmax
            top1[n] = be;
            topval[n] = best;
            ltok_e[tloc] = be;
            ltok_r[tloc] = atomicAdd(&lcnt[be], 1);
            atomicAdd(&lden[be], best);
        }
    }
    __syncthreads();
    if (tid < NEXP) {
        int c = lcnt[tid];
        lbase[tid] = c ? atomicAdd(&counts[tid], c) : 0;
        float dsum = lden[tid];
        if (dsum != 0.f) atomicAdd(&denom[tid], dsum);
    }
    __syncthreads();
    if (tid < 32) {
        int n = tok0 + tid;
        pos[n] = lbase[ltok_e[tid]] + ltok_r[tid];
    }
}

__global__ __launch_bounds__(256) void k_pre(
    const float* __restrict__ W1, const float* __restrict__ W2,
    u16* __restrict__ w1t, u16* __restrict__ w2t,
    const float* __restrict__ x, const float* __restrict__ Wg,
    int* __restrict__ top1, float* __restrict__ topval,
    int* __restrict__ pos, int* __restrict__ counts, float* __restrict__ denom,
    u16* __restrict__ xg) {
    __shared__ __align__(16) char smem[16832];
    const int b = blockIdx.x;
    if (b < 512) router_body(smem, b, x, Wg, top1, topval, pos, counts, denom, xg);
    else wt_body(smem, b - 512, W1, W2, w1t, w2t);
}

// ---------------- k_perm: sorted-slot -> token index -------------------------
__global__ __launch_bounds__(256) void k_perm(
    const int* __restrict__ top1, const int* __restrict__ pos,
    const int* __restrict__ counts, int* __restrict__ perm) {
    __shared__ int soffs[NEXP];
    if (threadIdx.x < NEXP) {
        int s = 0;
        for (int i = 0; i < (int)threadIdx.x; ++i) s += counts[i];
        soffs[threadIdx.x] = s;
    }
    __syncthreads();
    int n = blockIdx.x * 256 + threadIdx.x;
    perm[soffs[top1[n]] + pos[n]] = n;
}

// ---------------- GEMM1: hb = relu(x[perm] @ W1 + b1), tile 64x128x64 --------
// grid 4352 = 8 cx * 16 nt * 34 j; ms = cx + 8*j (64-row slots, XCD-affine).
__global__ __launch_bounds__(256) void k_ffn1(
    const u16* __restrict__ xg, const u16* __restrict__ w1t,
    const float* __restrict__ b1, const int* __restrict__ counts,
    const int* __restrict__ perm, u16* __restrict__ hb) {
    const int b = blockIdx.x;
    const int cx = b & 7;
    const int t = b >> 3;
    const int nt = t & 15;
    const int j = t >> 4;
    const int ms = cx + 8 * j;
    int e, row0, rows;
    if (!decode_ms64(counts, ms, e, row0, rows)) return;
    __shared__ u16 as[64 * 64];    // 8 KB
    __shared__ u16 bs[128 * 64];   // 16 KB
    const int tid = threadIdx.x;
    const int lane = tid & 63, wid = tid >> 6;
    const int wr = wid >> 1, wc = wid & 1;
    const int q = lane >> 4, l15 = lane & 15;
    const int c = tid & 7;
    // hoisted perm lookups: each thread stages 2 fixed A-rows for all K-steps
    const int ra0 = tid >> 3;           // 0..31
    const int ra1 = 32 + (tid >> 3);    // 32..63
    const int tokA0 = perm[row0 + (ra0 < rows ? ra0 : rows - 1)];
    const int tokA1 = perm[row0 + (ra1 < rows ? ra1 : rows - 1)];
    const int gcA0 = (c ^ (ra0 & 7)) * 8;
    const int gcA1 = (c ^ (ra1 & 7)) * 8;
    const u16* B = w1t + (size_t)e * FDIM * DIM + (size_t)(nt * 128) * DIM;
    f32x4 acc[2][4];
#pragma unroll
    for (int i = 0; i < 2; ++i)
#pragma unroll
        for (int jj = 0; jj < 4; ++jj) acc[i][jj] = f32x4{0.f, 0.f, 0.f, 0.f};

    for (int k0 = 0; k0 < DIM; k0 += 64) {
        gload16(xg + (size_t)tokA0 * DIM + k0 + gcA0, as + tid * 8);
        gload16(xg + (size_t)tokA1 * DIM + k0 + gcA1, as + (256 + tid) * 8);
#pragma unroll
        for (int it = 0; it < 4; ++it) {
            int chunk = it * 256 + tid;
            int row = chunk >> 3;
            int gcol = c ^ (row & 7);
            gload16(B + (size_t)row * DIM + k0 + gcol * 8, bs + chunk * 8);
        }
        __syncthreads();
#pragma unroll
        for (int ks = 0; ks < 64; ks += 32) {
            bf16x8 af[2], bfr[4];
#pragma unroll
            for (int mi = 0; mi < 2; ++mi) {
                int m = wr * 32 + mi * 16 + l15;
                int cc = ((ks >> 3) + q) ^ (m & 7);
                af[mi] = *(const bf16x8*)(as + m * 64 + cc * 8);
            }
#pragma unroll
            for (int ni = 0; ni < 4; ++ni) {
                int n = wc * 64 + ni * 16 + l15;
                int cc = ((ks >> 3) + q) ^ (n & 7);
                bfr[ni] = *(const bf16x8*)(bs + n * 64 + cc * 8);
            }
#pragma unroll
            for (int mi = 0; mi < 2; ++mi)
#pragma unroll
                for (int ni = 0; ni < 4; ++ni)
                    acc[mi][ni] = __builtin_amdgcn_mfma_f32_16x16x32_bf16(
                        af[mi], bfr[ni], acc[mi][ni], 0, 0, 0);
        }
        __syncthreads();
    }
    const float* b1e = b1 + e * FDIM + nt * 128;
    float bcol[4];
#pragma unroll
    for (int ni = 0; ni < 4; ++ni) bcol[ni] = b1e[wc * 64 + ni * 16 + l15];
#pragma unroll
    for (int mi = 0; mi < 2; ++mi) {
#pragma unroll
        for (int r = 0; r < 4; ++r) {
            int mrow = wr * 32 + mi * 16 + q * 4 + r;
            if (mrow >= rows) continue;
            size_t base = (size_t)(row0 + mrow) * FDIM + nt * 128;
#pragma unroll
            for (int ni = 0; ni < 4; ++ni) {
                float v = acc[mi][ni][r] + bcol[ni];
                v = v > 0.f ? v : 0.f;
                hb[base + wc * 64 + ni * 16 + l15] = f2bf(v);
            }
        }
    }
}

// ---------------- GEMM2: out[tok] = gate*(hb @ W2 + b2), tile 128x64x64 ------
// grid 1088 = 8 cx * 8 nt * 17 j; ms = cx + 8*j (128-row slots). R4 version.
__global__ __launch_bounds__(256) void k_ffn2(
    const u16* __restrict__ hb, const u16* __restrict__ w2t,
    const float* __restrict__ b2, const int* __restrict__ counts,
    const int* __restrict__ perm, const float* __restrict__ topval,
    const float* __restrict__ denom, float* __restrict__ out) {
    const int b = blockIdx.x;
    const int cx = b & 7;
    const int t = b >> 3;
    const int nt = t & 7;
    const int j = t >> 3;
    const int ms = cx + 8 * j;
    int e, row0, rows;
    if (!decode_ms128(counts, ms, e, row0, rows)) return;
    const float scale = 16384.0f / (denom[e] + 1e-6f);
    __shared__ u16 as[128 * 64];    // 16 KB
    __shared__ u16 bs[64 * 64];     // 8 KB
    const u16* B = w2t + (size_t)e * DIM * FDIM + (size_t)(nt * 64) * FDIM;
    const int tid = threadIdx.x;
    const int lane = tid & 63, w = tid >> 6;
    const int q = lane >> 4, l15 = lane & 15;
    const int c = tid & 7;
    f32x4 acc[2][4];
#pragma unroll
    for (int i = 0; i < 2; ++i)
#pragma unroll
        for (int jj = 0; jj < 4; ++jj) acc[i][jj] = f32x4{0.f, 0.f, 0.f, 0.f};

    for (int k0 = 0; k0 < FDIM; k0 += 64) {
#pragma unroll
        for (int it = 0; it < 4; ++it) {
            int chunk = it * 256 + tid;
            int row = chunk >> 3;
            int gcol = c ^ (row & 7);
            int rr = row < rows ? row : rows - 1;
            gload16(hb + (size_t)(row0 + rr) * FDIM + k0 + gcol * 8, as + chunk * 8);
        }
#pragma unroll
        for (int it = 0; it < 2; ++it) {
            int chunk = it * 256 + tid;
            int row = chunk >> 3;
            int gcol = c ^ (row & 7);
            gload16(B + (size_t)row * FDIM + k0 + gcol * 8, bs + chunk * 8);
        }
        __syncthreads();
#pragma unroll
        for (int ks = 0; ks < 64; ks += 32) {
            bf16x8 af[2], bfr[4];
#pragma unroll
            for (int mi = 0; mi < 2; ++mi) {
                int m = w * 32 + mi * 16 + l15;
                int cc = ((ks >> 3) + q) ^ (m & 7);
                af[mi] = *(const bf16x8*)(as + m * 64 + cc * 8);
            }
#pragma unroll
            for (int ni = 0; ni < 4; ++ni) {
                int n = ni * 16 + l15;
                int cc = ((ks >> 3) + q) ^ (n & 7);
                bfr[ni] = *(const bf16x8*)(bs + n * 64 + cc * 8);
            }
#pragma unroll
            for (int mi = 0; mi < 2; ++mi)
#pragma unroll
                for (int ni = 0; ni < 4; ++ni)
                    acc[mi][ni] = __builtin_amdgcn_mfma_f32_16x16x32_bf16(
                        af[mi], bfr[ni], acc[mi][ni], 0, 0, 0);
        }
        __syncthreads();
    }
    float bcol[4];
#pragma unroll
    for (int ni = 0; ni < 4; ++ni)
        bcol[ni] = b2[e * DIM + nt * 64 + ni * 16 + l15];
#pragma unroll
    for (int mi = 0; mi < 2; ++mi) {
#pragma unroll
        for (int r = 0; r < 4; ++r) {
            int mrow = w * 32 + mi * 16 + q * 4 + r;
            if (mrow >= rows) continue;
            int tok = perm[row0 + mrow];
            float g = topval[tok] * scale;
            size_t base = (size_t)tok * DIM + nt * 64;
#pragma unroll
            for (int ni = 0; ni < 4; ++ni) {
                float v = acc[mi][ni][r] + bcol[ni];
                out[base + ni * 16 + l15] = g * v;
            }
        }
    }
}

extern "C" void kernel_launch(void* const* d_in, const int* in_sizes, int n_in,
                              void* d_out, int out_size, void* d_ws, size_t ws_size,
                              hipStream_t stream) {
    const float* x  = (const float*)d_in[0];
    const float* Wg = (const float*)d_in[1];
    const float* W1 = (const float*)d_in[2];
    const float* b1 = (const float*)d_in[3];
    const float* W2 = (const float*)d_in[4];
    const float* b2 = (const float*)d_in[5];
    float* out = (float*)d_out;

    char* W = (char*)d_ws;
    int*   counts = (int*)W;                // 8 ints
    float* denom  = (float*)(W + 64);       // 8 floats
    int*   top1   = (int*)(W + 4096);
    float* topval = (float*)(W + 4096 + 65536);
    int*   pos    = (int*)(W + 4096 + 131072);
    int*   perm   = (int*)(W + 4096 + 196608);
    u16*   xg     = (u16*)(W + 266240);                  // N*D bf16 (token order)
    u16*   w1t    = xg  + (size_t)N_TOK * DIM;           // E*F*D bf16
    u16*   w2t    = w1t + (size_t)NEXP * FDIM * DIM;     // E*D*F bf16
    u16*   hb     = w2t + (size_t)NEXP * DIM * FDIM;     // N*F bf16 (sorted)

    hipMemsetAsync(W, 0, 128, stream);  // counts + denom
    k_pre<<<2560, 256, 0, stream>>>(W1, W2, w1t, w2t, x, Wg, top1, topval, pos,
                                    counts, denom, xg);
    k_perm<<<N_TOK / 256, 256, 0, stream>>>(top1, pos, counts, perm);
    k_ffn1<<<4352, 256, 0, stream>>>(xg, w1t, b1, counts, perm, hb);
    k_ffn2<<<1088, 256, 0, stream>>>(hb, w2t, b2, counts, perm, topval, denom, out);
}